// Round 7
// baseline (470.452 us; speedup 1.0000x reference)
//
#include <hip/hip_runtime.h>
#include <math.h>

#define N_SEQ   4096
#define C_TOT   768
#define NBLK    4
#define BS      192
#define B_BATCH 8
#define LAMBDA  0.01f
#define KTOT    384            // complex-as-real K (=2*BS)
#define APITCH  392            // LDS pitch in bf16 elems for MLP A-tile
#define SW(x)   ((x) ^ (((x) >> 5) & 31))   // FFT LDS bank swizzle
// NOTE (rounds 4/5 post-mortem): ASWZ LDS column swizzle cut bank conflicts
// 14.2M->3.1M but added ~320 MB of real HBM traffic to mlp (+103 us,
// reproduced on two containers). Reverted. The staging conflict costs ~7 us;
// per-lane store reordering would need dynamic vector indexing (scratch trap).

typedef short    bf16x8  __attribute__((ext_vector_type(8)));
typedef short    short4v __attribute__((ext_vector_type(4)));
typedef float    f32x4   __attribute__((ext_vector_type(4)));
typedef unsigned short ushort_t;

__device__ __forceinline__ unsigned short f2bf(float f) {
  unsigned int u = __float_as_uint(f);
  u = (u + 0x7FFFu + ((u >> 16) & 1u)) >> 16;   // RNE
  return (unsigned short)u;
}
__device__ __forceinline__ float b2f(unsigned short h) {
  return __uint_as_float(((unsigned int)h) << 16);
}

// ---------------------------------------------------------------------------
// Stockham radix-4 FFT core (N=4096 = 4^6), 1024 threads (one butterfly per
// thread per stage), SoA re/im LDS with XOR bank swizzle, ping-pong.
// 6 stages (even) => result back in Ar/Ai.
// ---------------------------------------------------------------------------
__device__ __forceinline__ void stockham_soa4(float* Ar, float* Ai,
                                              float* Br, float* Bi,
                                              int t, float sign) {
  float *sr = Ar, *si = Ai, *dr = Br, *di = Bi;
  float inv_p = 1.0f;
  int p = 1;
#pragma unroll
  for (int s = 0; s < 6; s++) {
    int i = t;                           // i in [0, 1024)
    int k = i & (p - 1);
    float a0r = sr[SW(i)],        a0i = si[SW(i)];
    float a1r = sr[SW(i + 1024)], a1i = si[SW(i + 1024)];
    float a2r = sr[SW(i + 2048)], a2i = si[SW(i + 2048)];
    float a3r = sr[SW(i + 3072)], a3i = si[SW(i + 3072)];
    float ang = sign * 1.5707963268f * inv_p * (float)k;   // sign*2pi*k/(4p)
    float s1, c1;
    __sincosf(ang, &s1, &c1);
    float c2 = c1 * c1 - s1 * s1, s2 = 2.0f * c1 * s1;
    float c3 = c1 * c2 - s1 * s2, s3 = c1 * s2 + s1 * c2;
    float b1r = c1 * a1r - s1 * a1i, b1i = c1 * a1i + s1 * a1r;
    float b2r = c2 * a2r - s2 * a2i, b2i = c2 * a2i + s2 * a2r;
    float b3r = c3 * a3r - s3 * a3i, b3i = c3 * a3i + s3 * a3r;
    float t0r = a0r + b2r, t0i = a0i + b2i;
    float t1r = a0r - b2r, t1i = a0i - b2i;
    float t2r = b1r + b3r, t2i = b1i + b3i;
    float t3r = b1r - b3r, t3i = b1i - b3i;
    int j = ((i - k) << 2) + k;
    dr[SW(j)]         = t0r + t2r;        di[SW(j)]         = t0i + t2i;
    dr[SW(j + p)]     = t1r - sign * t3i; di[SW(j + p)]     = t1i + sign * t3r;
    dr[SW(j + 2 * p)] = t0r - t2r;        di[SW(j + 2 * p)] = t0i - t2i;
    dr[SW(j + 3 * p)] = t1r + sign * t3i; di[SW(j + 3 * p)] = t1i - sign * t3r;
    __syncthreads();
    float* tp;
    tp = sr; sr = dr; dr = tp;
    tp = si; si = di; di = tp;
    p <<= 2;
    inv_p *= 0.25f;
  }
}

// ---------------------------------------------------------------------------
// Generic 64x64-tile transpose: src (B x R x C) -> dst (B x C x R), fp32.
// ---------------------------------------------------------------------------
__global__ __launch_bounds__(256) void transpose_kernel(
    const float* __restrict__ src, float* __restrict__ dst, int R, int C) {
  __shared__ float tile[64][65];
  const int c0 = blockIdx.x * 64, r0 = blockIdx.y * 64, b = blockIdx.z;
  const int tid = threadIdx.x;
#pragma unroll
  for (int it = 0; it < 4; it++) {
    int g = it * 256 + tid;            // 1024 float4 granules
    int r = g >> 4, q = g & 15;
    float4 v = *(const float4*)(src + ((size_t)b * R + r0 + r) * C + c0 + q * 4);
    tile[q * 4 + 0][r] = v.x;
    tile[q * 4 + 1][r] = v.y;
    tile[q * 4 + 2][r] = v.z;
    tile[q * 4 + 3][r] = v.w;
  }
  __syncthreads();
#pragma unroll
  for (int it = 0; it < 4; it++) {
    int g = it * 256 + tid;
    int c = g >> 4, w = g & 15;
    float4 v = make_float4(tile[c][w * 4 + 0], tile[c][w * 4 + 1],
                           tile[c][w * 4 + 2], tile[c][w * 4 + 3]);
    *(float4*)(dst + ((size_t)b * C + c0 + c) * R + r0 + w * 4) = v;
  }
}

// ---------------------------------------------------------------------------
// Stage 0: build complex-as-real weights in MFMA fragment-contiguous layout.
// ---------------------------------------------------------------------------
__global__ __launch_bounds__(256) void prep_kernel(
    const float* __restrict__ w1, const float* __restrict__ w2,
    ushort_t* __restrict__ Bc) {
  int idx = blockIdx.x * 256 + threadIdx.x;        // [0, 2*4*147456)
  int layer = idx / 589824; int r = idx - layer * 589824;
  int kb = r / 147456;      int r2 = r - kb * 147456;
  int jc = r2 / 6144;       int r3 = r2 - jc * 6144;
  int kc = r3 / 512;        int r4 = r3 - kc * 512;
  int lane = r4 >> 3;       int e = r4 & 7;
  int j = jc * 16 + (lane & 15);
  int k = kc * 32 + (lane >> 4) * 8 + e;
  const float* w = layer ? w2 : w1;
  float v;
  if (k < 192) {
    v = (j < 192) ? w[(kb * 192 + k) * 192 + j]
                  : w[((4 + kb) * 192 + k) * 192 + (j - 192)];
  } else {
    int k2 = k - 192;
    v = (j < 192) ? -w[((4 + kb) * 192 + k2) * 192 + j]
                  :  w[(kb * 192 + k2) * 192 + (j - 192)];
  }
  Bc[idx] = f2bf(v);
}

// ---------------------------------------------------------------------------
// Stage 1: forward FFT, two real columns packed per workgroup (1024 thr).
// xT (b,c,n) fp32 -> Fr/Fi (b,c,n) bf16.
// ---------------------------------------------------------------------------
__global__ __launch_bounds__(1024, 8) void fft_fwd_kernel(
    const float* __restrict__ xT, ushort_t* __restrict__ Fr,
    ushort_t* __restrict__ Fi) {
  __shared__ float Ar[N_SEQ], Ai[N_SEQ], Br[N_SEQ], Bi[N_SEQ];
  const int q = blockIdx.x, b = blockIdx.y;        // q in [0,384)
  const int c1 = 2 * q;
  const int t = threadIdx.x;
  const float* p1 = xT + ((size_t)b * C_TOT + c1) * N_SEQ;
  const float* p2 = p1 + N_SEQ;
#pragma unroll
  for (int m = 0; m < 4; m++) {
    int i = t + m * 1024;
    Ar[SW(i)] = p1[i];
    Ai[SW(i)] = p2[i];
  }
  __syncthreads();
  stockham_soa4(Ar, Ai, Br, Bi, t, -1.0f);
  ushort_t* fr1 = Fr + ((size_t)b * C_TOT + c1) * N_SEQ;
  ushort_t* fi1 = Fi + ((size_t)b * C_TOT + c1) * N_SEQ;
#pragma unroll
  for (int m = 0; m < 4; m++) {
    int k = t + m * 1024;
    int km = (N_SEQ - k) & (N_SEQ - 1);
    float a = Ar[SW(k)], bb = Ai[SW(k)], c = Ar[SW(km)], d = Ai[SW(km)];
    fr1[k]         = f2bf(0.5f * (a + c));    // X1.re
    fi1[k]         = f2bf(0.5f * (bb - d));   // X1.im
    fr1[N_SEQ + k] = f2bf(0.5f * (bb + d));   // X2.re
    fi1[N_SEQ + k] = f2bf(0.5f * (c - a));    // X2.im
  }
}

// ---------------------------------------------------------------------------
// Stage 2 (FUSED): MFMA 2-layer complex MLP with in-kernel forward DFT-4
// across blocks + transpose staging. One wg = (b, kb, 64-n tile).
// NOW 512 threads / 8 waves (was 256/4): round-6 counters showed mlp is
// latency-bound (HBM 18%, Mfma 26%, VALU 33%, occupancy 29% = 9.3 waves/CU).
// Same 50 KB LDS -> 3 wg/CU; 8 waves/wg -> 24 waves/CU. Each wave owns 48
// output cols (3 ct). acc halves to 12 f32x4 so VGPR fits the 6-waves/SIMD cap.
// ---------------------------------------------------------------------------
__global__ __launch_bounds__(512, 6) void mlp_kernel(
    const ushort_t* __restrict__ Fr, const ushort_t* __restrict__ Fi,
    const ushort_t* __restrict__ Bc,       // fragment-contiguous (see prep)
    const float* __restrict__ b1g, const float* __restrict__ b2g,
    ushort_t* __restrict__ Or, ushort_t* __restrict__ Oi) {
  __shared__ ushort_t Abuf[64 * APITCH];
  const int nt = blockIdx.x, kb = blockIdx.y, b = blockIdx.z;
  const int n0 = nt * 64;
  const int tid = threadIdx.x;
  const int lane = tid & 63, wave = tid >> 6;       // wave in [0,8)
  const int fr = lane & 15, fg = lane >> 4;
  const int col0 = wave * 48;

  // ---- fused DFT-4 across channel blocks + 1/128 ortho scale + transpose ----
  {
    const size_t S = (size_t)BS * N_SEQ;
    const float s = 0.0078125f;                       // 1/128
#pragma unroll
    for (int it = 0; it < 3; it++) {
      int g = it * 512 + tid;            // 1536 granules = 192 d x 8 n-octets
      int d = g >> 3, n8 = g & 7;
      size_t bse = ((size_t)(b * C_TOT + d)) * N_SEQ + n0 + n8 * 8;
      bf16x8 y0r = *(const bf16x8*)(Fr + bse);
      bf16x8 y0i = *(const bf16x8*)(Fi + bse);
      bf16x8 y1r = *(const bf16x8*)(Fr + bse + S);
      bf16x8 y1i = *(const bf16x8*)(Fi + bse + S);
      bf16x8 y2r = *(const bf16x8*)(Fr + bse + 2 * S);
      bf16x8 y2i = *(const bf16x8*)(Fi + bse + 2 * S);
      bf16x8 y3r = *(const bf16x8*)(Fr + bse + 3 * S);
      bf16x8 y3i = *(const bf16x8*)(Fi + bse + 3 * S);
#pragma unroll
      for (int e = 0; e < 8; e++) {
        float a0r = b2f((unsigned short)y0r[e]), a0i = b2f((unsigned short)y0i[e]);
        float a1r = b2f((unsigned short)y1r[e]), a1i = b2f((unsigned short)y1i[e]);
        float a2r = b2f((unsigned short)y2r[e]), a2i = b2f((unsigned short)y2i[e]);
        float a3r = b2f((unsigned short)y3r[e]), a3i = b2f((unsigned short)y3i[e]);
        float zr, zi;
        if (kb == 0)      { zr = a0r + a1r + a2r + a3r; zi = a0i + a1i + a2i + a3i; }
        else if (kb == 1) { zr = a0r + a1i - a2r - a3i; zi = a0i - a1r - a2i + a3r; }
        else if (kb == 2) { zr = a0r - a1r + a2r - a3r; zi = a0i - a1i + a2i - a3i; }
        else              { zr = a0r - a1i - a2r + a3i; zi = a0i + a1r - a2i - a3r; }
        int n = n8 * 8 + e;
        Abuf[n * APITCH + d]       = f2bf(zr * s);
        Abuf[n * APITCH + 192 + d] = f2bf(zi * s);
      }
    }
  }
  __syncthreads();

  // per-(layer,kb) fragment bases; wave's jc0 = wave*3, ct step = 6144
  const ushort_t* B1 = Bc + (size_t)kb * 147456 + (size_t)wave * 18432 +
                       (size_t)lane * 8;
  const ushort_t* B2 = B1 + 589824;

  f32x4 acc[4][3];
  bf16x8 bf0[3], bf1[3], afr[4];

  auto loadB = [&](const ushort_t* Bb, int kc, bf16x8* dst) {
#pragma unroll
    for (int ct = 0; ct < 3; ct++)
      dst[ct] = *(const bf16x8*)(Bb + (size_t)kc * 512 + ct * 6144);
  };
  auto doK = [&](int kc, bf16x8* bw) {
#pragma unroll
    for (int rt = 0; rt < 4; rt++)
      afr[rt] = *(const bf16x8*)(&Abuf[(rt * 16 + fr) * APITCH + kc * 32 + fg * 8]);
#pragma unroll
    for (int rt = 0; rt < 4; rt++)
#pragma unroll
      for (int ct = 0; ct < 3; ct++)
        acc[rt][ct] = __builtin_amdgcn_mfma_f32_16x16x32_bf16(
            afr[rt], bw[ct], acc[rt][ct], 0, 0, 0);
  };

  // ---- layer 1 ----
#pragma unroll
  for (int rt = 0; rt < 4; rt++)
#pragma unroll
    for (int ct = 0; ct < 3; ct++) acc[rt][ct] = 0.0f;
  loadB(B1, 0, bf0);
#pragma unroll
  for (int kc2 = 0; kc2 < 6; kc2++) {
    loadB(B1, 2 * kc2 + 1, bf1);
    doK(2 * kc2, bf0);
    if (kc2 < 5) loadB(B1, 2 * kc2 + 2, bf0);
    doK(2 * kc2 + 1, bf1);
  }

  // ---- H = relu(acc + b1) -> back into Abuf (bf16) ----
  __syncthreads();   // all waves done reading A
#pragma unroll
  for (int ct = 0; ct < 3; ct++) {
    int j = col0 + ct * 16 + fr;
    float bias = (j < 192) ? b1g[kb * 192 + j] : b1g[768 + kb * 192 + (j - 192)];
#pragma unroll
    for (int rt = 0; rt < 4; rt++)
#pragma unroll
      for (int reg = 0; reg < 4; reg++) {
        float v = acc[rt][ct][reg] + bias;
        v = fmaxf(v, 0.0f);
        Abuf[(rt * 16 + fg * 4 + reg) * APITCH + j] = f2bf(v);
      }
  }
  __syncthreads();

  // ---- layer 2 ----
#pragma unroll
  for (int rt = 0; rt < 4; rt++)
#pragma unroll
    for (int ct = 0; ct < 3; ct++) acc[rt][ct] = 0.0f;
  loadB(B2, 0, bf0);
#pragma unroll
  for (int kc2 = 0; kc2 < 6; kc2++) {
    loadB(B2, 2 * kc2 + 1, bf1);
    doK(2 * kc2, bf0);
    if (kc2 < 5) loadB(B2, 2 * kc2 + 2, bf0);
    doK(2 * kc2 + 1, bf1);
  }

  // ---- epilogue: bias + softshrink -> bf16 planes (b,c,n) ----
#pragma unroll
  for (int ct = 0; ct < 3; ct++) {
    int j = col0 + ct * 16 + fr;
    float bias;
    ushort_t* plane;
    if (j < 192) {
      bias = b2g[kb * 192 + j];
      plane = Or + ((size_t)(b * C_TOT + kb * 192 + j)) * N_SEQ;
    } else {
      bias = b2g[768 + kb * 192 + (j - 192)];
      plane = Oi + ((size_t)(b * C_TOT + kb * 192 + (j - 192))) * N_SEQ;
    }
#pragma unroll
    for (int rt = 0; rt < 4; rt++) {
      short4v pk;
#pragma unroll
      for (int reg = 0; reg < 4; reg++) {
        float v = acc[rt][ct][reg] + bias;
        v = (v > LAMBDA) ? (v - LAMBDA) : ((v < -LAMBDA) ? (v + LAMBDA) : 0.0f);
        pk[reg] = (short)f2bf(v);
      }
      *(short4v*)(plane + n0 + rt * 16 + fg * 4) = pk;
    }
  }
}

// ---------------------------------------------------------------------------
// Stage 3 (FUSED): inverse FFT (1024 thr) with in-kernel inverse DFT-4 across
// blocks in the load phase. Output channel c1=2q maps to (spatial block
// jb = c1/192, d = c1%192); o_jb[d] = (1/128) * sum_kb z_kb[d] * i^(jb*kb).
// Then Hermitian projection + packed inverse FFT.
// ---------------------------------------------------------------------------
__global__ __launch_bounds__(1024, 8) void fft_inv_kernel(
    const ushort_t* __restrict__ Or, const ushort_t* __restrict__ Oi,
    float* __restrict__ yT) {
  __shared__ float Ar[N_SEQ], Ai[N_SEQ], Br[N_SEQ], Bi[N_SEQ];
  const int q = blockIdx.x, b = blockIdx.y;
  const int c1 = 2 * q;
  const int jb = c1 / 192;             // spatial block (same for c1, c1+1)
  const int d  = c1 - jb * 192;        // even
  const int t = threadIdx.x;
  const size_t S = (size_t)BS * N_SEQ;
  const float s = 1.0f / 128.0f;
  const size_t base0 = ((size_t)b * C_TOT + d) * N_SEQ;
  {
    int i0 = t * 4;                    // 1024 threads x 4 = 4096
#pragma unroll
    for (int col = 0; col < 2; col++) {
      size_t bse = base0 + (size_t)col * N_SEQ + i0;
      short4v z0r = *(const short4v*)(Or + bse);
      short4v z0i = *(const short4v*)(Oi + bse);
      short4v z1r = *(const short4v*)(Or + bse + S);
      short4v z1i = *(const short4v*)(Oi + bse + S);
      short4v z2r = *(const short4v*)(Or + bse + 2 * S);
      short4v z2i = *(const short4v*)(Oi + bse + 2 * S);
      short4v z3r = *(const short4v*)(Or + bse + 3 * S);
      short4v z3i = *(const short4v*)(Oi + bse + 3 * S);
      float* Dr = col ? Br : Ar;
      float* Di = col ? Bi : Ai;
#pragma unroll
      for (int e = 0; e < 4; e++) {
        float a0r = b2f((unsigned short)z0r[e]), a0i = b2f((unsigned short)z0i[e]);
        float a1r = b2f((unsigned short)z1r[e]), a1i = b2f((unsigned short)z1i[e]);
        float a2r = b2f((unsigned short)z2r[e]), a2i = b2f((unsigned short)z2i[e]);
        float a3r = b2f((unsigned short)z3r[e]), a3i = b2f((unsigned short)z3i[e]);
        float orr, oii;
        if (jb == 0)      { orr = a0r + a1r + a2r + a3r; oii = a0i + a1i + a2i + a3i; }
        else if (jb == 1) { orr = a0r - a1i - a2r + a3i; oii = a0i + a1r - a2i - a3r; }
        else if (jb == 2) { orr = a0r - a1r + a2r - a3r; oii = a0i - a1i + a2i - a3i; }
        else              { orr = a0r + a1i - a2r - a3i; oii = a0i - a1r - a2i + a3r; }
        int i = i0 + e;
        Dr[SW(i)] = orr * s;
        Di[SW(i)] = oii * s;
      }
    }
  }
  __syncthreads();
  float wr[4], wi[4];
#pragma unroll
  for (int m = 0; m < 4; m++) {
    int k = t + m * 1024;
    int km = (N_SEQ - k) & (N_SEQ - 1);
    float zh1r = 0.5f * (Ar[SW(k)] + Ar[SW(km)]);
    float zh1i = 0.5f * (Ai[SW(k)] - Ai[SW(km)]);
    float zh2r = 0.5f * (Br[SW(k)] + Br[SW(km)]);
    float zh2i = 0.5f * (Bi[SW(k)] - Bi[SW(km)]);
    wr[m] = zh1r - zh2i;
    wi[m] = zh1i + zh2r;
  }
  __syncthreads();
#pragma unroll
  for (int m = 0; m < 4; m++) {
    int k = t + m * 1024;
    Ar[SW(k)] = wr[m];
    Ai[SW(k)] = wi[m];
  }
  __syncthreads();
  stockham_soa4(Ar, Ai, Br, Bi, t, +1.0f);
  float* y1 = yT + ((size_t)b * C_TOT + c1) * N_SEQ;
#pragma unroll
  for (int m = 0; m < 4; m++) {
    int i = t + m * 1024;
    y1[i]         = Ar[SW(i)];
    y1[N_SEQ + i] = Ai[SW(i)];
  }
}

// ---------------------------------------------------------------------------
extern "C" void kernel_launch(void* const* d_in, const int* in_sizes, int n_in,
                              void* d_out, int out_size, void* d_ws, size_t ws_size,
                              hipStream_t stream) {
  const float* x  = (const float*)d_in[0];
  const float* w1 = (const float*)d_in[1];
  const float* b1 = (const float*)d_in[2];
  const float* w2 = (const float*)d_in[3];
  const float* b2 = (const float*)d_in[4];
  float* out = (float*)d_out;

  const size_t P = (size_t)B_BATCH * C_TOT * N_SEQ;       // 25,165,824 elems
  // ws layout (bytes):
  //   [0, 2P):   Fr (P bf16)            -> later yT low half
  //   [2P, 4P):  Fi (P bf16)            -> later yT high half
  //   [4P, 8P):  xT (P fp32)            -> later Or (P bf16) + Oi (P bf16)
  //   Bc at 8P: 2*589824 bf16
  // Serial reuse is safe: fft_fwd consumes xT before mlp writes Or/Oi there;
  // mlp consumes Fr/Fi before fft_inv writes yT there.
  const size_t need = 8 * P + 2 * 589824 * sizeof(ushort_t);  // 203,685,888 B
  if (ws_size < need) return;
  char* base = (char*)d_ws;
  ushort_t* Fr = (ushort_t*)base;
  ushort_t* Fi = (ushort_t*)(base + 2 * P);
  float*    xT = (float*)(base + 4 * P);
  ushort_t* Or = (ushort_t*)(base + 4 * P);
  ushort_t* Oi = (ushort_t*)(base + 6 * P);
  float*    yT = (float*)base;
  ushort_t* Bc = (ushort_t*)(base + 8 * P);

  hipLaunchKernelGGL(prep_kernel, dim3(4608), dim3(256), 0, stream, w1, w2, Bc);
  // x (b,n,c) -> xT (b,c,n)
  hipLaunchKernelGGL(transpose_kernel, dim3(C_TOT / 64, N_SEQ / 64, B_BATCH),
                     dim3(256), 0, stream, x, xT, N_SEQ, C_TOT);
  hipLaunchKernelGGL(fft_fwd_kernel, dim3(C_TOT / 2, B_BATCH), dim3(1024), 0,
                     stream, xT, Fr, Fi);
  hipLaunchKernelGGL(mlp_kernel, dim3(N_SEQ / 64, NBLK, B_BATCH), dim3(512),
                     0, stream, Fr, Fi, Bc, b1, b2, Or, Oi);
  hipLaunchKernelGGL(fft_inv_kernel, dim3(C_TOT / 2, B_BATCH), dim3(1024), 0,
                     stream, Or, Oi, yT);
  // yT (b,c,n) -> out (b,n,c)
  hipLaunchKernelGGL(transpose_kernel, dim3(N_SEQ / 64, C_TOT / 64, B_BATCH),
                     dim3(256), 0, stream, yT, out, C_TOT, N_SEQ);
}

// Round 8
// 455.583 us; speedup vs baseline: 1.0326x; 1.0326x over previous
//
#include <hip/hip_runtime.h>
#include <math.h>

#define N_SEQ   4096
#define C_TOT   768
#define NBLK    4
#define BS      192
#define B_BATCH 8
#define LAMBDA  0.01f
#define KTOT    384            // complex-as-real K (=2*BS)
#define APITCH  392            // LDS pitch in bf16 elems for MLP A-tile
#define SW(x)   ((x) ^ (((x) >> 5) & 31))   // FFT LDS bank swizzle
// SPILL CANARY (r7 post-mortem): __launch_bounds__(512,6) caps VGPR at 85.
// r7's live set (~90) spilled acc to scratch: VGPR_Count 40, WRITE_SIZE
// 100->319 MB, mlp +46 us. Same signature as ASWZ r4/5 (XOR addressing ->
// pressure -> spill). This version trims live set to ~79: single-buffer B
// (12 regs), per-rt A-fragment (4 regs). If VGPR_Count <= 50 or WRITE >=
// 200 MB again: abandon 512-thr mlp, revert to r6 (256 thr, 127 us).

typedef short    bf16x8  __attribute__((ext_vector_type(8)));
typedef short    short4v __attribute__((ext_vector_type(4)));
typedef float    f32x4   __attribute__((ext_vector_type(4)));
typedef unsigned short ushort_t;

__device__ __forceinline__ unsigned short f2bf(float f) {
  unsigned int u = __float_as_uint(f);
  u = (u + 0x7FFFu + ((u >> 16) & 1u)) >> 16;   // RNE
  return (unsigned short)u;
}
__device__ __forceinline__ float b2f(unsigned short h) {
  return __uint_as_float(((unsigned int)h) << 16);
}

// ---------------------------------------------------------------------------
// Stockham radix-4 FFT core (N=4096 = 4^6), 1024 threads (one butterfly per
// thread per stage), SoA re/im LDS with XOR bank swizzle, ping-pong.
// 6 stages (even) => result back in Ar/Ai.
// ---------------------------------------------------------------------------
__device__ __forceinline__ void stockham_soa4(float* Ar, float* Ai,
                                              float* Br, float* Bi,
                                              int t, float sign) {
  float *sr = Ar, *si = Ai, *dr = Br, *di = Bi;
  float inv_p = 1.0f;
  int p = 1;
#pragma unroll
  for (int s = 0; s < 6; s++) {
    int i = t;                           // i in [0, 1024)
    int k = i & (p - 1);
    float a0r = sr[SW(i)],        a0i = si[SW(i)];
    float a1r = sr[SW(i + 1024)], a1i = si[SW(i + 1024)];
    float a2r = sr[SW(i + 2048)], a2i = si[SW(i + 2048)];
    float a3r = sr[SW(i + 3072)], a3i = si[SW(i + 3072)];
    float ang = sign * 1.5707963268f * inv_p * (float)k;   // sign*2pi*k/(4p)
    float s1, c1;
    __sincosf(ang, &s1, &c1);
    float c2 = c1 * c1 - s1 * s1, s2 = 2.0f * c1 * s1;
    float c3 = c1 * c2 - s1 * s2, s3 = c1 * s2 + s1 * c2;
    float b1r = c1 * a1r - s1 * a1i, b1i = c1 * a1i + s1 * a1r;
    float b2r = c2 * a2r - s2 * a2i, b2i = c2 * a2i + s2 * a2r;
    float b3r = c3 * a3r - s3 * a3i, b3i = c3 * a3i + s3 * a3r;
    float t0r = a0r + b2r, t0i = a0i + b2i;
    float t1r = a0r - b2r, t1i = a0i - b2i;
    float t2r = b1r + b3r, t2i = b1i + b3i;
    float t3r = b1r - b3r, t3i = b1i - b3i;
    int j = ((i - k) << 2) + k;
    dr[SW(j)]         = t0r + t2r;        di[SW(j)]         = t0i + t2i;
    dr[SW(j + p)]     = t1r - sign * t3i; di[SW(j + p)]     = t1i + sign * t3r;
    dr[SW(j + 2 * p)] = t0r - t2r;        di[SW(j + 2 * p)] = t0i - t2i;
    dr[SW(j + 3 * p)] = t1r + sign * t3i; di[SW(j + 3 * p)] = t1i - sign * t3r;
    __syncthreads();
    float* tp;
    tp = sr; sr = dr; dr = tp;
    tp = si; si = di; di = tp;
    p <<= 2;
    inv_p *= 0.25f;
  }
}

// ---------------------------------------------------------------------------
// Generic 64x64-tile transpose: src (B x R x C) -> dst (B x C x R), fp32.
// ---------------------------------------------------------------------------
__global__ __launch_bounds__(256) void transpose_kernel(
    const float* __restrict__ src, float* __restrict__ dst, int R, int C) {
  __shared__ float tile[64][65];
  const int c0 = blockIdx.x * 64, r0 = blockIdx.y * 64, b = blockIdx.z;
  const int tid = threadIdx.x;
#pragma unroll
  for (int it = 0; it < 4; it++) {
    int g = it * 256 + tid;            // 1024 float4 granules
    int r = g >> 4, q = g & 15;
    float4 v = *(const float4*)(src + ((size_t)b * R + r0 + r) * C + c0 + q * 4);
    tile[q * 4 + 0][r] = v.x;
    tile[q * 4 + 1][r] = v.y;
    tile[q * 4 + 2][r] = v.z;
    tile[q * 4 + 3][r] = v.w;
  }
  __syncthreads();
#pragma unroll
  for (int it = 0; it < 4; it++) {
    int g = it * 256 + tid;
    int c = g >> 4, w = g & 15;
    float4 v = make_float4(tile[c][w * 4 + 0], tile[c][w * 4 + 1],
                           tile[c][w * 4 + 2], tile[c][w * 4 + 3]);
    *(float4*)(dst + ((size_t)b * C + c0 + c) * R + r0 + w * 4) = v;
  }
}

// ---------------------------------------------------------------------------
// Stage 0: build complex-as-real weights in MFMA fragment-contiguous layout.
// ---------------------------------------------------------------------------
__global__ __launch_bounds__(256) void prep_kernel(
    const float* __restrict__ w1, const float* __restrict__ w2,
    ushort_t* __restrict__ Bc) {
  int idx = blockIdx.x * 256 + threadIdx.x;        // [0, 2*4*147456)
  int layer = idx / 589824; int r = idx - layer * 589824;
  int kb = r / 147456;      int r2 = r - kb * 147456;
  int jc = r2 / 6144;       int r3 = r2 - jc * 6144;
  int kc = r3 / 512;        int r4 = r3 - kc * 512;
  int lane = r4 >> 3;       int e = r4 & 7;
  int j = jc * 16 + (lane & 15);
  int k = kc * 32 + (lane >> 4) * 8 + e;
  const float* w = layer ? w2 : w1;
  float v;
  if (k < 192) {
    v = (j < 192) ? w[(kb * 192 + k) * 192 + j]
                  : w[((4 + kb) * 192 + k) * 192 + (j - 192)];
  } else {
    int k2 = k - 192;
    v = (j < 192) ? -w[((4 + kb) * 192 + k2) * 192 + j]
                  :  w[(kb * 192 + k2) * 192 + (j - 192)];
  }
  Bc[idx] = f2bf(v);
}

// ---------------------------------------------------------------------------
// Stage 1: forward FFT, two real columns packed per workgroup (1024 thr).
// xT (b,c,n) fp32 -> Fr/Fi (b,c,n) bf16.
// ---------------------------------------------------------------------------
__global__ __launch_bounds__(1024, 8) void fft_fwd_kernel(
    const float* __restrict__ xT, ushort_t* __restrict__ Fr,
    ushort_t* __restrict__ Fi) {
  __shared__ float Ar[N_SEQ], Ai[N_SEQ], Br[N_SEQ], Bi[N_SEQ];
  const int q = blockIdx.x, b = blockIdx.y;        // q in [0,384)
  const int c1 = 2 * q;
  const int t = threadIdx.x;
  const float* p1 = xT + ((size_t)b * C_TOT + c1) * N_SEQ;
  const float* p2 = p1 + N_SEQ;
#pragma unroll
  for (int m = 0; m < 4; m++) {
    int i = t + m * 1024;
    Ar[SW(i)] = p1[i];
    Ai[SW(i)] = p2[i];
  }
  __syncthreads();
  stockham_soa4(Ar, Ai, Br, Bi, t, -1.0f);
  ushort_t* fr1 = Fr + ((size_t)b * C_TOT + c1) * N_SEQ;
  ushort_t* fi1 = Fi + ((size_t)b * C_TOT + c1) * N_SEQ;
#pragma unroll
  for (int m = 0; m < 4; m++) {
    int k = t + m * 1024;
    int km = (N_SEQ - k) & (N_SEQ - 1);
    float a = Ar[SW(k)], bb = Ai[SW(k)], c = Ar[SW(km)], d = Ai[SW(km)];
    fr1[k]         = f2bf(0.5f * (a + c));    // X1.re
    fi1[k]         = f2bf(0.5f * (bb - d));   // X1.im
    fr1[N_SEQ + k] = f2bf(0.5f * (bb + d));   // X2.re
    fi1[N_SEQ + k] = f2bf(0.5f * (c - a));    // X2.im
  }
}

// ---------------------------------------------------------------------------
// Stage 2 (FUSED): MFMA 2-layer complex MLP with in-kernel forward DFT-4
// across blocks + transpose staging. One wg = (b, kb, 64-n tile).
// 512 threads / 8 waves, __launch_bounds__(512,6): 3 wg/CU (LDS) x 8 waves
// = 24 waves/CU. Register budget engineered for the 85-VGPR cap: acc 48 +
// single-buffered B 12 + per-rt A-fragment 4 + misc ~15 = ~79. TLP (6
// waves/SIMD) hides the B-load and LDS latency that the dropped
// double-buffer used to cover.
// ---------------------------------------------------------------------------
__global__ __launch_bounds__(512, 6) void mlp_kernel(
    const ushort_t* __restrict__ Fr, const ushort_t* __restrict__ Fi,
    const ushort_t* __restrict__ Bc,       // fragment-contiguous (see prep)
    const float* __restrict__ b1g, const float* __restrict__ b2g,
    ushort_t* __restrict__ Or, ushort_t* __restrict__ Oi) {
  __shared__ ushort_t Abuf[64 * APITCH];
  const int nt = blockIdx.x, kb = blockIdx.y, b = blockIdx.z;
  const int n0 = nt * 64;
  const int tid = threadIdx.x;
  const int lane = tid & 63, wave = tid >> 6;       // wave in [0,8)
  const int fr = lane & 15, fg = lane >> 4;
  const int col0 = wave * 48;

  // ---- fused DFT-4 across channel blocks + 1/128 ortho scale + transpose ----
  {
    const size_t S = (size_t)BS * N_SEQ;
    const float s = 0.0078125f;                       // 1/128
#pragma unroll
    for (int it = 0; it < 3; it++) {
      int g = it * 512 + tid;            // 1536 granules = 192 d x 8 n-octets
      int d = g >> 3, n8 = g & 7;
      size_t bse = ((size_t)(b * C_TOT + d)) * N_SEQ + n0 + n8 * 8;
      bf16x8 y0r = *(const bf16x8*)(Fr + bse);
      bf16x8 y0i = *(const bf16x8*)(Fi + bse);
      bf16x8 y1r = *(const bf16x8*)(Fr + bse + S);
      bf16x8 y1i = *(const bf16x8*)(Fi + bse + S);
      bf16x8 y2r = *(const bf16x8*)(Fr + bse + 2 * S);
      bf16x8 y2i = *(const bf16x8*)(Fi + bse + 2 * S);
      bf16x8 y3r = *(const bf16x8*)(Fr + bse + 3 * S);
      bf16x8 y3i = *(const bf16x8*)(Fi + bse + 3 * S);
#pragma unroll
      for (int e = 0; e < 8; e++) {
        float a0r = b2f((unsigned short)y0r[e]), a0i = b2f((unsigned short)y0i[e]);
        float a1r = b2f((unsigned short)y1r[e]), a1i = b2f((unsigned short)y1i[e]);
        float a2r = b2f((unsigned short)y2r[e]), a2i = b2f((unsigned short)y2i[e]);
        float a3r = b2f((unsigned short)y3r[e]), a3i = b2f((unsigned short)y3i[e]);
        float zr, zi;
        if (kb == 0)      { zr = a0r + a1r + a2r + a3r; zi = a0i + a1i + a2i + a3i; }
        else if (kb == 1) { zr = a0r + a1i - a2r - a3i; zi = a0i - a1r - a2i + a3r; }
        else if (kb == 2) { zr = a0r - a1r + a2r - a3r; zi = a0i - a1i + a2i - a3i; }
        else              { zr = a0r - a1i - a2r + a3i; zi = a0i + a1r - a2i - a3r; }
        int n = n8 * 8 + e;
        Abuf[n * APITCH + d]       = f2bf(zr * s);
        Abuf[n * APITCH + 192 + d] = f2bf(zi * s);
      }
    }
  }
  __syncthreads();

  // per-(layer,kb) fragment bases; wave owns cols [wave*48, wave*48+48)
  const ushort_t* B1 = Bc + (size_t)kb * 147456 + (size_t)wave * 18432 +
                       (size_t)lane * 8;
  const ushort_t* B2 = B1 + 589824;

  f32x4 acc[4][3];
  bf16x8 bw[3];

  auto layer = [&](const ushort_t* Bb) {
#pragma unroll
    for (int rt = 0; rt < 4; rt++)
#pragma unroll
      for (int ct = 0; ct < 3; ct++) acc[rt][ct] = 0.0f;
#pragma unroll
    for (int kc = 0; kc < 12; kc++) {
#pragma unroll
      for (int ct = 0; ct < 3; ct++)
        bw[ct] = *(const bf16x8*)(Bb + (size_t)kc * 512 + ct * 6144);
#pragma unroll
      for (int rt = 0; rt < 4; rt++) {
        bf16x8 a = *(const bf16x8*)(
            &Abuf[(rt * 16 + fr) * APITCH + kc * 32 + fg * 8]);
#pragma unroll
        for (int ct = 0; ct < 3; ct++)
          acc[rt][ct] = __builtin_amdgcn_mfma_f32_16x16x32_bf16(
              a, bw[ct], acc[rt][ct], 0, 0, 0);
      }
    }
  };

  // ---- layer 1 ----
  layer(B1);

  // ---- H = relu(acc + b1) -> back into Abuf (bf16) ----
  __syncthreads();   // all waves done reading A
#pragma unroll
  for (int ct = 0; ct < 3; ct++) {
    int j = col0 + ct * 16 + fr;
    float bias = (j < 192) ? b1g[kb * 192 + j] : b1g[768 + kb * 192 + (j - 192)];
#pragma unroll
    for (int rt = 0; rt < 4; rt++)
#pragma unroll
      for (int reg = 0; reg < 4; reg++) {
        float v = acc[rt][ct][reg] + bias;
        v = fmaxf(v, 0.0f);
        Abuf[(rt * 16 + fg * 4 + reg) * APITCH + j] = f2bf(v);
      }
  }
  __syncthreads();

  // ---- layer 2 ----
  layer(B2);

  // ---- epilogue: bias + softshrink -> bf16 planes (b,c,n) ----
#pragma unroll
  for (int ct = 0; ct < 3; ct++) {
    int j = col0 + ct * 16 + fr;
    float bias;
    ushort_t* plane;
    if (j < 192) {
      bias = b2g[kb * 192 + j];
      plane = Or + ((size_t)(b * C_TOT + kb * 192 + j)) * N_SEQ;
    } else {
      bias = b2g[768 + kb * 192 + (j - 192)];
      plane = Oi + ((size_t)(b * C_TOT + kb * 192 + (j - 192))) * N_SEQ;
    }
#pragma unroll
    for (int rt = 0; rt < 4; rt++) {
      short4v pk;
#pragma unroll
      for (int reg = 0; reg < 4; reg++) {
        float v = acc[rt][ct][reg] + bias;
        v = (v > LAMBDA) ? (v - LAMBDA) : ((v < -LAMBDA) ? (v + LAMBDA) : 0.0f);
        pk[reg] = (short)f2bf(v);
      }
      *(short4v*)(plane + n0 + rt * 16 + fg * 4) = pk;
    }
  }
}

// ---------------------------------------------------------------------------
// Stage 3 (FUSED): inverse FFT (1024 thr) with in-kernel inverse DFT-4 across
// blocks in the load phase. Output channel c1=2q maps to (spatial block
// jb = c1/192, d = c1%192); o_jb[d] = (1/128) * sum_kb z_kb[d] * i^(jb*kb).
// Then Hermitian projection + packed inverse FFT.
// ---------------------------------------------------------------------------
__global__ __launch_bounds__(1024, 8) void fft_inv_kernel(
    const ushort_t* __restrict__ Or, const ushort_t* __restrict__ Oi,
    float* __restrict__ yT) {
  __shared__ float Ar[N_SEQ], Ai[N_SEQ], Br[N_SEQ], Bi[N_SEQ];
  const int q = blockIdx.x, b = blockIdx.y;
  const int c1 = 2 * q;
  const int jb = c1 / 192;             // spatial block (same for c1, c1+1)
  const int d  = c1 - jb * 192;        // even
  const int t = threadIdx.x;
  const size_t S = (size_t)BS * N_SEQ;
  const float s = 1.0f / 128.0f;
  const size_t base0 = ((size_t)b * C_TOT + d) * N_SEQ;
  {
    int i0 = t * 4;                    // 1024 threads x 4 = 4096
#pragma unroll
    for (int col = 0; col < 2; col++) {
      size_t bse = base0 + (size_t)col * N_SEQ + i0;
      short4v z0r = *(const short4v*)(Or + bse);
      short4v z0i = *(const short4v*)(Oi + bse);
      short4v z1r = *(const short4v*)(Or + bse + S);
      short4v z1i = *(const short4v*)(Oi + bse + S);
      short4v z2r = *(const short4v*)(Or + bse + 2 * S);
      short4v z2i = *(const short4v*)(Oi + bse + 2 * S);
      short4v z3r = *(const short4v*)(Or + bse + 3 * S);
      short4v z3i = *(const short4v*)(Oi + bse + 3 * S);
      float* Dr = col ? Br : Ar;
      float* Di = col ? Bi : Ai;
#pragma unroll
      for (int e = 0; e < 4; e++) {
        float a0r = b2f((unsigned short)z0r[e]), a0i = b2f((unsigned short)z0i[e]);
        float a1r = b2f((unsigned short)z1r[e]), a1i = b2f((unsigned short)z1i[e]);
        float a2r = b2f((unsigned short)z2r[e]), a2i = b2f((unsigned short)z2i[e]);
        float a3r = b2f((unsigned short)z3r[e]), a3i = b2f((unsigned short)z3i[e]);
        float orr, oii;
        if (jb == 0)      { orr = a0r + a1r + a2r + a3r; oii = a0i + a1i + a2i + a3i; }
        else if (jb == 1) { orr = a0r - a1i - a2r + a3i; oii = a0i + a1r - a2i - a3r; }
        else if (jb == 2) { orr = a0r - a1r + a2r - a3r; oii = a0i - a1i + a2i - a3i; }
        else              { orr = a0r + a1i - a2r - a3i; oii = a0i - a1r - a2i + a3r; }
        int i = i0 + e;
        Dr[SW(i)] = orr * s;
        Di[SW(i)] = oii * s;
      }
    }
  }
  __syncthreads();
  float wr[4], wi[4];
#pragma unroll
  for (int m = 0; m < 4; m++) {
    int k = t + m * 1024;
    int km = (N_SEQ - k) & (N_SEQ - 1);
    float zh1r = 0.5f * (Ar[SW(k)] + Ar[SW(km)]);
    float zh1i = 0.5f * (Ai[SW(k)] - Ai[SW(km)]);
    float zh2r = 0.5f * (Br[SW(k)] + Br[SW(km)]);
    float zh2i = 0.5f * (Bi[SW(k)] - Bi[SW(km)]);
    wr[m] = zh1r - zh2i;
    wi[m] = zh1i + zh2r;
  }
  __syncthreads();
#pragma unroll
  for (int m = 0; m < 4; m++) {
    int k = t + m * 1024;
    Ar[SW(k)] = wr[m];
    Ai[SW(k)] = wi[m];
  }
  __syncthreads();
  stockham_soa4(Ar, Ai, Br, Bi, t, +1.0f);
  float* y1 = yT + ((size_t)b * C_TOT + c1) * N_SEQ;
#pragma unroll
  for (int m = 0; m < 4; m++) {
    int i = t + m * 1024;
    y1[i]         = Ar[SW(i)];
    y1[N_SEQ + i] = Ai[SW(i)];
  }
}

// ---------------------------------------------------------------------------
extern "C" void kernel_launch(void* const* d_in, const int* in_sizes, int n_in,
                              void* d_out, int out_size, void* d_ws, size_t ws_size,
                              hipStream_t stream) {
  const float* x  = (const float*)d_in[0];
  const float* w1 = (const float*)d_in[1];
  const float* b1 = (const float*)d_in[2];
  const float* w2 = (const float*)d_in[3];
  const float* b2 = (const float*)d_in[4];
  float* out = (float*)d_out;

  const size_t P = (size_t)B_BATCH * C_TOT * N_SEQ;       // 25,165,824 elems
  // ws layout (bytes):
  //   [0, 2P):   Fr (P bf16)            -> later yT low half
  //   [2P, 4P):  Fi (P bf16)            -> later yT high half
  //   [4P, 8P):  xT (P fp32)            -> later Or (P bf16) + Oi (P bf16)
  //   Bc at 8P: 2*589824 bf16
  // Serial reuse is safe: fft_fwd consumes xT before mlp writes Or/Oi there;
  // mlp consumes Fr/Fi before fft_inv writes yT there.
  const size_t need = 8 * P + 2 * 589824 * sizeof(ushort_t);  // 203,685,888 B
  if (ws_size < need) return;
  char* base = (char*)d_ws;
  ushort_t* Fr = (ushort_t*)base;
  ushort_t* Fi = (ushort_t*)(base + 2 * P);
  float*    xT = (float*)(base + 4 * P);
  ushort_t* Or = (ushort_t*)(base + 4 * P);
  ushort_t* Oi = (ushort_t*)(base + 6 * P);
  float*    yT = (float*)base;
  ushort_t* Bc = (ushort_t*)(base + 8 * P);

  hipLaunchKernelGGL(prep_kernel, dim3(4608), dim3(256), 0, stream, w1, w2, Bc);
  // x (b,n,c) -> xT (b,c,n)
  hipLaunchKernelGGL(transpose_kernel, dim3(C_TOT / 64, N_SEQ / 64, B_BATCH),
                     dim3(256), 0, stream, x, xT, N_SEQ, C_TOT);
  hipLaunchKernelGGL(fft_fwd_kernel, dim3(C_TOT / 2, B_BATCH), dim3(1024), 0,
                     stream, xT, Fr, Fi);
  hipLaunchKernelGGL(mlp_kernel, dim3(N_SEQ / 64, NBLK, B_BATCH), dim3(512),
                     0, stream, Fr, Fi, Bc, b1, b2, Or, Oi);
  hipLaunchKernelGGL(fft_inv_kernel, dim3(C_TOT / 2, B_BATCH), dim3(1024), 0,
                     stream, Or, Oi, yT);
  // yT (b,c,n) -> out (b,n,c)
  hipLaunchKernelGGL(transpose_kernel, dim3(N_SEQ / 64, C_TOT / 64, B_BATCH),
                     dim3(256), 0, stream, yT, out, C_TOT, N_SEQ);
}

// Round 9
// 438.679 us; speedup vs baseline: 1.0724x; 1.0385x over previous
//
#include <hip/hip_runtime.h>
#include <math.h>

#define N_SEQ   4096
#define C_TOT   768
#define NBLK    4
#define BS      192
#define B_BATCH 8
#define LAMBDA  0.01f
#define KTOT    384            // complex-as-real K (=2*BS)
#define APITCH  392            // LDS pitch in bf16 elems for MLP A-tile
#define SW(x)   ((x) ^ (((x) >> 5) & 31))   // FFT LDS bank swizzle
// SPILL LEDGER: (512,6) cap=85 spilled TWICE (r7 ~90 live; r8 ~79 live —
// unified VGPR/AGPR file: 48-reg acc in AGPRs + 40 arch VGPRs = 88 > 85).
// Signature: VGPR_Count 40, WRITE_SIZE 250-320 MB, FETCH +80 MB. 6 waves/SIMD
// is structurally infeasible with a 48-reg accumulator. This round: (512,4)
// cap=128, dbuf structure (~103 live) -> no spill, 16 waves/CU vs r6's 9.3.
// Canary: VGPR<=60 or WRITE>=200MB => revert mlp to r6 (256 thr, 127 us).

typedef short    bf16x8  __attribute__((ext_vector_type(8)));
typedef short    short4v __attribute__((ext_vector_type(4)));
typedef float    f32x4   __attribute__((ext_vector_type(4)));
typedef unsigned short ushort_t;

__device__ __forceinline__ unsigned short f2bf(float f) {
  unsigned int u = __float_as_uint(f);
  u = (u + 0x7FFFu + ((u >> 16) & 1u)) >> 16;   // RNE
  return (unsigned short)u;
}
__device__ __forceinline__ float b2f(unsigned short h) {
  return __uint_as_float(((unsigned int)h) << 16);
}

// ---------------------------------------------------------------------------
// Stockham radix-4 FFT core (N=4096 = 4^6), 1024 threads (one butterfly per
// thread per stage), SoA re/im LDS with XOR bank swizzle, ping-pong.
// 6 stages (even) => result back in Ar/Ai.
// ---------------------------------------------------------------------------
__device__ __forceinline__ void stockham_soa4(float* Ar, float* Ai,
                                              float* Br, float* Bi,
                                              int t, float sign) {
  float *sr = Ar, *si = Ai, *dr = Br, *di = Bi;
  float inv_p = 1.0f;
  int p = 1;
#pragma unroll
  for (int s = 0; s < 6; s++) {
    int i = t;                           // i in [0, 1024)
    int k = i & (p - 1);
    float a0r = sr[SW(i)],        a0i = si[SW(i)];
    float a1r = sr[SW(i + 1024)], a1i = si[SW(i + 1024)];
    float a2r = sr[SW(i + 2048)], a2i = si[SW(i + 2048)];
    float a3r = sr[SW(i + 3072)], a3i = si[SW(i + 3072)];
    float ang = sign * 1.5707963268f * inv_p * (float)k;   // sign*2pi*k/(4p)
    float s1, c1;
    __sincosf(ang, &s1, &c1);
    float c2 = c1 * c1 - s1 * s1, s2 = 2.0f * c1 * s1;
    float c3 = c1 * c2 - s1 * s2, s3 = c1 * s2 + s1 * c2;
    float b1r = c1 * a1r - s1 * a1i, b1i = c1 * a1i + s1 * a1r;
    float b2r = c2 * a2r - s2 * a2i, b2i = c2 * a2i + s2 * a2r;
    float b3r = c3 * a3r - s3 * a3i, b3i = c3 * a3i + s3 * a3r;
    float t0r = a0r + b2r, t0i = a0i + b2i;
    float t1r = a0r - b2r, t1i = a0i - b2i;
    float t2r = b1r + b3r, t2i = b1i + b3i;
    float t3r = b1r - b3r, t3i = b1i - b3i;
    int j = ((i - k) << 2) + k;
    dr[SW(j)]         = t0r + t2r;        di[SW(j)]         = t0i + t2i;
    dr[SW(j + p)]     = t1r - sign * t3i; di[SW(j + p)]     = t1i + sign * t3r;
    dr[SW(j + 2 * p)] = t0r - t2r;        di[SW(j + 2 * p)] = t0i - t2i;
    dr[SW(j + 3 * p)] = t1r + sign * t3i; di[SW(j + 3 * p)] = t1i - sign * t3r;
    __syncthreads();
    float* tp;
    tp = sr; sr = dr; dr = tp;
    tp = si; si = di; di = tp;
    p <<= 2;
    inv_p *= 0.25f;
  }
}

// ---------------------------------------------------------------------------
// Generic 64x64-tile transpose: src (B x R x C) -> dst (B x C x R), fp32.
// ---------------------------------------------------------------------------
__global__ __launch_bounds__(256) void transpose_kernel(
    const float* __restrict__ src, float* __restrict__ dst, int R, int C) {
  __shared__ float tile[64][65];
  const int c0 = blockIdx.x * 64, r0 = blockIdx.y * 64, b = blockIdx.z;
  const int tid = threadIdx.x;
#pragma unroll
  for (int it = 0; it < 4; it++) {
    int g = it * 256 + tid;            // 1024 float4 granules
    int r = g >> 4, q = g & 15;
    float4 v = *(const float4*)(src + ((size_t)b * R + r0 + r) * C + c0 + q * 4);
    tile[q * 4 + 0][r] = v.x;
    tile[q * 4 + 1][r] = v.y;
    tile[q * 4 + 2][r] = v.z;
    tile[q * 4 + 3][r] = v.w;
  }
  __syncthreads();
#pragma unroll
  for (int it = 0; it < 4; it++) {
    int g = it * 256 + tid;
    int c = g >> 4, w = g & 15;
    float4 v = make_float4(tile[c][w * 4 + 0], tile[c][w * 4 + 1],
                           tile[c][w * 4 + 2], tile[c][w * 4 + 3]);
    *(float4*)(dst + ((size_t)b * C + c0 + c) * R + r0 + w * 4) = v;
  }
}

// ---------------------------------------------------------------------------
// Stage 0: build complex-as-real weights in MFMA fragment-contiguous layout.
// ---------------------------------------------------------------------------
__global__ __launch_bounds__(256) void prep_kernel(
    const float* __restrict__ w1, const float* __restrict__ w2,
    ushort_t* __restrict__ Bc) {
  int idx = blockIdx.x * 256 + threadIdx.x;        // [0, 2*4*147456)
  int layer = idx / 589824; int r = idx - layer * 589824;
  int kb = r / 147456;      int r2 = r - kb * 147456;
  int jc = r2 / 6144;       int r3 = r2 - jc * 6144;
  int kc = r3 / 512;        int r4 = r3 - kc * 512;
  int lane = r4 >> 3;       int e = r4 & 7;
  int j = jc * 16 + (lane & 15);
  int k = kc * 32 + (lane >> 4) * 8 + e;
  const float* w = layer ? w2 : w1;
  float v;
  if (k < 192) {
    v = (j < 192) ? w[(kb * 192 + k) * 192 + j]
                  : w[((4 + kb) * 192 + k) * 192 + (j - 192)];
  } else {
    int k2 = k - 192;
    v = (j < 192) ? -w[((4 + kb) * 192 + k2) * 192 + j]
                  :  w[(kb * 192 + k2) * 192 + (j - 192)];
  }
  Bc[idx] = f2bf(v);
}

// ---------------------------------------------------------------------------
// Stage 1: forward FFT, two real columns packed per workgroup (1024 thr).
// xT (b,c,n) fp32 -> Fr/Fi (b,c,n) bf16.
// ---------------------------------------------------------------------------
__global__ __launch_bounds__(1024, 8) void fft_fwd_kernel(
    const float* __restrict__ xT, ushort_t* __restrict__ Fr,
    ushort_t* __restrict__ Fi) {
  __shared__ float Ar[N_SEQ], Ai[N_SEQ], Br[N_SEQ], Bi[N_SEQ];
  const int q = blockIdx.x, b = blockIdx.y;        // q in [0,384)
  const int c1 = 2 * q;
  const int t = threadIdx.x;
  const float* p1 = xT + ((size_t)b * C_TOT + c1) * N_SEQ;
  const float* p2 = p1 + N_SEQ;
#pragma unroll
  for (int m = 0; m < 4; m++) {
    int i = t + m * 1024;
    Ar[SW(i)] = p1[i];
    Ai[SW(i)] = p2[i];
  }
  __syncthreads();
  stockham_soa4(Ar, Ai, Br, Bi, t, -1.0f);
  ushort_t* fr1 = Fr + ((size_t)b * C_TOT + c1) * N_SEQ;
  ushort_t* fi1 = Fi + ((size_t)b * C_TOT + c1) * N_SEQ;
#pragma unroll
  for (int m = 0; m < 4; m++) {
    int k = t + m * 1024;
    int km = (N_SEQ - k) & (N_SEQ - 1);
    float a = Ar[SW(k)], bb = Ai[SW(k)], c = Ar[SW(km)], d = Ai[SW(km)];
    fr1[k]         = f2bf(0.5f * (a + c));    // X1.re
    fi1[k]         = f2bf(0.5f * (bb - d));   // X1.im
    fr1[N_SEQ + k] = f2bf(0.5f * (bb + d));   // X2.re
    fi1[N_SEQ + k] = f2bf(0.5f * (c - a));    // X2.im
  }
}

// ---------------------------------------------------------------------------
// Stage 2 (FUSED): MFMA 2-layer complex MLP with in-kernel forward DFT-4
// across blocks + transpose staging. One wg = (b, kb, 64-n tile).
// 512 threads / 8 waves, __launch_bounds__(512,4): cap 128 VGPR -> no spill
// (live ~103: acc 48 + bf dbuf 24 + afr 16 + misc). 2 wg x 8 waves = 16
// waves/CU vs r6's measured 9.3. Each wave owns 48 output cols (3 ct),
// B fragments double-buffered as in the known-good r6 structure.
// ---------------------------------------------------------------------------
__global__ __launch_bounds__(512, 4) void mlp_kernel(
    const ushort_t* __restrict__ Fr, const ushort_t* __restrict__ Fi,
    const ushort_t* __restrict__ Bc,       // fragment-contiguous (see prep)
    const float* __restrict__ b1g, const float* __restrict__ b2g,
    ushort_t* __restrict__ Or, ushort_t* __restrict__ Oi) {
  __shared__ ushort_t Abuf[64 * APITCH];
  const int nt = blockIdx.x, kb = blockIdx.y, b = blockIdx.z;
  const int n0 = nt * 64;
  const int tid = threadIdx.x;
  const int lane = tid & 63, wave = tid >> 6;       // wave in [0,8)
  const int fr = lane & 15, fg = lane >> 4;
  const int col0 = wave * 48;

  // ---- fused DFT-4 across channel blocks + 1/128 ortho scale + transpose ----
  {
    const size_t S = (size_t)BS * N_SEQ;
    const float s = 0.0078125f;                       // 1/128
#pragma unroll
    for (int it = 0; it < 3; it++) {
      int g = it * 512 + tid;            // 1536 granules = 192 d x 8 n-octets
      int d = g >> 3, n8 = g & 7;
      size_t bse = ((size_t)(b * C_TOT + d)) * N_SEQ + n0 + n8 * 8;
      bf16x8 y0r = *(const bf16x8*)(Fr + bse);
      bf16x8 y0i = *(const bf16x8*)(Fi + bse);
      bf16x8 y1r = *(const bf16x8*)(Fr + bse + S);
      bf16x8 y1i = *(const bf16x8*)(Fi + bse + S);
      bf16x8 y2r = *(const bf16x8*)(Fr + bse + 2 * S);
      bf16x8 y2i = *(const bf16x8*)(Fi + bse + 2 * S);
      bf16x8 y3r = *(const bf16x8*)(Fr + bse + 3 * S);
      bf16x8 y3i = *(const bf16x8*)(Fi + bse + 3 * S);
#pragma unroll
      for (int e = 0; e < 8; e++) {
        float a0r = b2f((unsigned short)y0r[e]), a0i = b2f((unsigned short)y0i[e]);
        float a1r = b2f((unsigned short)y1r[e]), a1i = b2f((unsigned short)y1i[e]);
        float a2r = b2f((unsigned short)y2r[e]), a2i = b2f((unsigned short)y2i[e]);
        float a3r = b2f((unsigned short)y3r[e]), a3i = b2f((unsigned short)y3i[e]);
        float zr, zi;
        if (kb == 0)      { zr = a0r + a1r + a2r + a3r; zi = a0i + a1i + a2i + a3i; }
        else if (kb == 1) { zr = a0r + a1i - a2r - a3i; zi = a0i - a1r - a2i + a3r; }
        else if (kb == 2) { zr = a0r - a1r + a2r - a3r; zi = a0i - a1i + a2i - a3i; }
        else              { zr = a0r - a1i - a2r + a3i; zi = a0i + a1r - a2i - a3r; }
        int n = n8 * 8 + e;
        Abuf[n * APITCH + d]       = f2bf(zr * s);
        Abuf[n * APITCH + 192 + d] = f2bf(zi * s);
      }
    }
  }
  __syncthreads();

  // per-(layer,kb) fragment bases; wave owns cols [wave*48, wave*48+48)
  const ushort_t* B1 = Bc + (size_t)kb * 147456 + (size_t)wave * 18432 +
                       (size_t)lane * 8;
  const ushort_t* B2 = B1 + 589824;

  f32x4 acc[4][3];
  bf16x8 bf0[3], bf1[3], afr[4];

  auto loadB = [&](const ushort_t* Bb, int kc, bf16x8* dst) {
#pragma unroll
    for (int ct = 0; ct < 3; ct++)
      dst[ct] = *(const bf16x8*)(Bb + (size_t)kc * 512 + ct * 6144);
  };
  auto doK = [&](int kc, bf16x8* bw) {
#pragma unroll
    for (int rt = 0; rt < 4; rt++)
      afr[rt] = *(const bf16x8*)(&Abuf[(rt * 16 + fr) * APITCH + kc * 32 + fg * 8]);
#pragma unroll
    for (int rt = 0; rt < 4; rt++)
#pragma unroll
      for (int ct = 0; ct < 3; ct++)
        acc[rt][ct] = __builtin_amdgcn_mfma_f32_16x16x32_bf16(
            afr[rt], bw[ct], acc[rt][ct], 0, 0, 0);
  };

  // ---- layer 1 ----
#pragma unroll
  for (int rt = 0; rt < 4; rt++)
#pragma unroll
    for (int ct = 0; ct < 3; ct++) acc[rt][ct] = 0.0f;
  loadB(B1, 0, bf0);
#pragma unroll
  for (int kc2 = 0; kc2 < 6; kc2++) {
    loadB(B1, 2 * kc2 + 1, bf1);
    doK(2 * kc2, bf0);
    if (kc2 < 5) loadB(B1, 2 * kc2 + 2, bf0);
    doK(2 * kc2 + 1, bf1);
  }

  // ---- H = relu(acc + b1) -> back into Abuf (bf16) ----
  __syncthreads();   // all waves done reading A
#pragma unroll
  for (int ct = 0; ct < 3; ct++) {
    int j = col0 + ct * 16 + fr;
    float bias = (j < 192) ? b1g[kb * 192 + j] : b1g[768 + kb * 192 + (j - 192)];
#pragma unroll
    for (int rt = 0; rt < 4; rt++)
#pragma unroll
      for (int reg = 0; reg < 4; reg++) {
        float v = acc[rt][ct][reg] + bias;
        v = fmaxf(v, 0.0f);
        Abuf[(rt * 16 + fg * 4 + reg) * APITCH + j] = f2bf(v);
      }
  }
  __syncthreads();

  // ---- layer 2 ----
#pragma unroll
  for (int rt = 0; rt < 4; rt++)
#pragma unroll
    for (int ct = 0; ct < 3; ct++) acc[rt][ct] = 0.0f;
  loadB(B2, 0, bf0);
#pragma unroll
  for (int kc2 = 0; kc2 < 6; kc2++) {
    loadB(B2, 2 * kc2 + 1, bf1);
    doK(2 * kc2, bf0);
    if (kc2 < 5) loadB(B2, 2 * kc2 + 2, bf0);
    doK(2 * kc2 + 1, bf1);
  }

  // ---- epilogue: bias + softshrink -> bf16 planes (b,c,n) ----
#pragma unroll
  for (int ct = 0; ct < 3; ct++) {
    int j = col0 + ct * 16 + fr;
    float bias;
    ushort_t* plane;
    if (j < 192) {
      bias = b2g[kb * 192 + j];
      plane = Or + ((size_t)(b * C_TOT + kb * 192 + j)) * N_SEQ;
    } else {
      bias = b2g[768 + kb * 192 + (j - 192)];
      plane = Oi + ((size_t)(b * C_TOT + kb * 192 + (j - 192))) * N_SEQ;
    }
#pragma unroll
    for (int rt = 0; rt < 4; rt++) {
      short4v pk;
#pragma unroll
      for (int reg = 0; reg < 4; reg++) {
        float v = acc[rt][ct][reg] + bias;
        v = (v > LAMBDA) ? (v - LAMBDA) : ((v < -LAMBDA) ? (v + LAMBDA) : 0.0f);
        pk[reg] = (short)f2bf(v);
      }
      *(short4v*)(plane + n0 + rt * 16 + fg * 4) = pk;
    }
  }
}

// ---------------------------------------------------------------------------
// Stage 3 (FUSED): inverse FFT (1024 thr) with in-kernel inverse DFT-4 across
// blocks in the load phase. Output channel c1=2q maps to (spatial block
// jb = c1/192, d = c1%192); o_jb[d] = (1/128) * sum_kb z_kb[d] * i^(jb*kb).
// Then Hermitian projection + packed inverse FFT.
// ---------------------------------------------------------------------------
__global__ __launch_bounds__(1024, 8) void fft_inv_kernel(
    const ushort_t* __restrict__ Or, const ushort_t* __restrict__ Oi,
    float* __restrict__ yT) {
  __shared__ float Ar[N_SEQ], Ai[N_SEQ], Br[N_SEQ], Bi[N_SEQ];
  const int q = blockIdx.x, b = blockIdx.y;
  const int c1 = 2 * q;
  const int jb = c1 / 192;             // spatial block (same for c1, c1+1)
  const int d  = c1 - jb * 192;        // even
  const int t = threadIdx.x;
  const size_t S = (size_t)BS * N_SEQ;
  const float s = 1.0f / 128.0f;
  const size_t base0 = ((size_t)b * C_TOT + d) * N_SEQ;
  {
    int i0 = t * 4;                    // 1024 threads x 4 = 4096
#pragma unroll
    for (int col = 0; col < 2; col++) {
      size_t bse = base0 + (size_t)col * N_SEQ + i0;
      short4v z0r = *(const short4v*)(Or + bse);
      short4v z0i = *(const short4v*)(Oi + bse);
      short4v z1r = *(const short4v*)(Or + bse + S);
      short4v z1i = *(const short4v*)(Oi + bse + S);
      short4v z2r = *(const short4v*)(Or + bse + 2 * S);
      short4v z2i = *(const short4v*)(Oi + bse + 2 * S);
      short4v z3r = *(const short4v*)(Or + bse + 3 * S);
      short4v z3i = *(const short4v*)(Oi + bse + 3 * S);
      float* Dr = col ? Br : Ar;
      float* Di = col ? Bi : Ai;
#pragma unroll
      for (int e = 0; e < 4; e++) {
        float a0r = b2f((unsigned short)z0r[e]), a0i = b2f((unsigned short)z0i[e]);
        float a1r = b2f((unsigned short)z1r[e]), a1i = b2f((unsigned short)z1i[e]);
        float a2r = b2f((unsigned short)z2r[e]), a2i = b2f((unsigned short)z2i[e]);
        float a3r = b2f((unsigned short)z3r[e]), a3i = b2f((unsigned short)z3i[e]);
        float orr, oii;
        if (jb == 0)      { orr = a0r + a1r + a2r + a3r; oii = a0i + a1i + a2i + a3i; }
        else if (jb == 1) { orr = a0r - a1i - a2r + a3i; oii = a0i + a1r - a2i - a3r; }
        else if (jb == 2) { orr = a0r - a1r + a2r - a3r; oii = a0i - a1i + a2i - a3i; }
        else              { orr = a0r + a1i - a2r - a3i; oii = a0i - a1r - a2i + a3r; }
        int i = i0 + e;
        Dr[SW(i)] = orr * s;
        Di[SW(i)] = oii * s;
      }
    }
  }
  __syncthreads();
  float wr[4], wi[4];
#pragma unroll
  for (int m = 0; m < 4; m++) {
    int k = t + m * 1024;
    int km = (N_SEQ - k) & (N_SEQ - 1);
    float zh1r = 0.5f * (Ar[SW(k)] + Ar[SW(km)]);
    float zh1i = 0.5f * (Ai[SW(k)] - Ai[SW(km)]);
    float zh2r = 0.5f * (Br[SW(k)] + Br[SW(km)]);
    float zh2i = 0.5f * (Bi[SW(k)] - Bi[SW(km)]);
    wr[m] = zh1r - zh2i;
    wi[m] = zh1i + zh2r;
  }
  __syncthreads();
#pragma unroll
  for (int m = 0; m < 4; m++) {
    int k = t + m * 1024;
    Ar[SW(k)] = wr[m];
    Ai[SW(k)] = wi[m];
  }
  __syncthreads();
  stockham_soa4(Ar, Ai, Br, Bi, t, +1.0f);
  float* y1 = yT + ((size_t)b * C_TOT + c1) * N_SEQ;
#pragma unroll
  for (int m = 0; m < 4; m++) {
    int i = t + m * 1024;
    y1[i]         = Ar[SW(i)];
    y1[N_SEQ + i] = Ai[SW(i)];
  }
}

// ---------------------------------------------------------------------------
extern "C" void kernel_launch(void* const* d_in, const int* in_sizes, int n_in,
                              void* d_out, int out_size, void* d_ws, size_t ws_size,
                              hipStream_t stream) {
  const float* x  = (const float*)d_in[0];
  const float* w1 = (const float*)d_in[1];
  const float* b1 = (const float*)d_in[2];
  const float* w2 = (const float*)d_in[3];
  const float* b2 = (const float*)d_in[4];
  float* out = (float*)d_out;

  const size_t P = (size_t)B_BATCH * C_TOT * N_SEQ;       // 25,165,824 elems
  // ws layout (bytes):
  //   [0, 2P):   Fr (P bf16)            -> later yT low half
  //   [2P, 4P):  Fi (P bf16)            -> later yT high half
  //   [4P, 8P):  xT (P fp32)            -> later Or (P bf16) + Oi (P bf16)
  //   Bc at 8P: 2*589824 bf16
  // Serial reuse is safe: fft_fwd consumes xT before mlp writes Or/Oi there;
  // mlp consumes Fr/Fi before fft_inv writes yT there.
  const size_t need = 8 * P + 2 * 589824 * sizeof(ushort_t);  // 203,685,888 B
  if (ws_size < need) return;
  char* base = (char*)d_ws;
  ushort_t* Fr = (ushort_t*)base;
  ushort_t* Fi = (ushort_t*)(base + 2 * P);
  float*    xT = (float*)(base + 4 * P);
  ushort_t* Or = (ushort_t*)(base + 4 * P);
  ushort_t* Oi = (ushort_t*)(base + 6 * P);
  float*    yT = (float*)base;
  ushort_t* Bc = (ushort_t*)(base + 8 * P);

  hipLaunchKernelGGL(prep_kernel, dim3(4608), dim3(256), 0, stream, w1, w2, Bc);
  // x (b,n,c) -> xT (b,c,n)
  hipLaunchKernelGGL(transpose_kernel, dim3(C_TOT / 64, N_SEQ / 64, B_BATCH),
                     dim3(256), 0, stream, x, xT, N_SEQ, C_TOT);
  hipLaunchKernelGGL(fft_fwd_kernel, dim3(C_TOT / 2, B_BATCH), dim3(1024), 0,
                     stream, xT, Fr, Fi);
  hipLaunchKernelGGL(mlp_kernel, dim3(N_SEQ / 64, NBLK, B_BATCH), dim3(512),
                     0, stream, Fr, Fi, Bc, b1, b2, Or, Oi);
  hipLaunchKernelGGL(fft_inv_kernel, dim3(C_TOT / 2, B_BATCH), dim3(1024), 0,
                     stream, Or, Oi, yT);
  // yT (b,c,n) -> out (b,n,c)
  hipLaunchKernelGGL(transpose_kernel, dim3(N_SEQ / 64, C_TOT / 64, B_BATCH),
                     dim3(256), 0, stream, yT, out, C_TOT, N_SEQ);
}

// Round 10
// 414.874 us; speedup vs baseline: 1.1340x; 1.0574x over previous
//
#include <hip/hip_runtime.h>
#include <math.h>

#define N_SEQ   4096
#define C_TOT   768
#define NBLK    4
#define BS      192
#define B_BATCH 8
#define LAMBDA  0.01f
#define KTOT    384            // complex-as-real K (=2*BS)
#define APITCH  392            // LDS pitch in bf16 elems for MLP A-tile
#define SW(x)   ((x) ^ (((x) >> 5) & 31))   // FFT LDS bank swizzle
// GPAD (r10): +16B pad every 8 rows of Abuf. Any 16B-aligned pitch makes the
// 8-row stride = 0 mod 32 banks, so the staging write (8 n8-groups x 8 d)
// was a 16-way conflict (17.3M cycles, r9). AROW spreads the n8 groups by 8
// dwords -> staging writes hit all 32 banks (2 lanes/bank = same-dword byte
// merge = free). Fragment-read bank histogram is UNCHANGED (verified by
// hand); H-writes stay <=2-way; rows stay 16B-aligned. Pad term is
// loop-invariant (plain add, no XOR) to avoid the r4/r5 scratch pathology.
// SPILL/SCRATCH CANARY: VGPR<=60 or WRITE>=200MB => revert this change.
#define AROW(n) ((n) * APITCH + (((n) >> 3) << 3))

typedef short    bf16x8  __attribute__((ext_vector_type(8)));
typedef short    short4v __attribute__((ext_vector_type(4)));
typedef float    f32x4   __attribute__((ext_vector_type(4)));
typedef unsigned short ushort_t;

__device__ __forceinline__ unsigned short f2bf(float f) {
  unsigned int u = __float_as_uint(f);
  u = (u + 0x7FFFu + ((u >> 16) & 1u)) >> 16;   // RNE
  return (unsigned short)u;
}
__device__ __forceinline__ float b2f(unsigned short h) {
  return __uint_as_float(((unsigned int)h) << 16);
}

// ---------------------------------------------------------------------------
// Stockham radix-4 FFT core (N=4096 = 4^6), 1024 threads (one butterfly per
// thread per stage), SoA re/im LDS with XOR bank swizzle, ping-pong.
// 6 stages (even) => result back in Ar/Ai.
// ---------------------------------------------------------------------------
__device__ __forceinline__ void stockham_soa4(float* Ar, float* Ai,
                                              float* Br, float* Bi,
                                              int t, float sign) {
  float *sr = Ar, *si = Ai, *dr = Br, *di = Bi;
  float inv_p = 1.0f;
  int p = 1;
#pragma unroll
  for (int s = 0; s < 6; s++) {
    int i = t;                           // i in [0, 1024)
    int k = i & (p - 1);
    float a0r = sr[SW(i)],        a0i = si[SW(i)];
    float a1r = sr[SW(i + 1024)], a1i = si[SW(i + 1024)];
    float a2r = sr[SW(i + 2048)], a2i = si[SW(i + 2048)];
    float a3r = sr[SW(i + 3072)], a3i = si[SW(i + 3072)];
    float ang = sign * 1.5707963268f * inv_p * (float)k;   // sign*2pi*k/(4p)
    float s1, c1;
    __sincosf(ang, &s1, &c1);
    float c2 = c1 * c1 - s1 * s1, s2 = 2.0f * c1 * s1;
    float c3 = c1 * c2 - s1 * s2, s3 = c1 * s2 + s1 * c2;
    float b1r = c1 * a1r - s1 * a1i, b1i = c1 * a1i + s1 * a1r;
    float b2r = c2 * a2r - s2 * a2i, b2i = c2 * a2i + s2 * a2r;
    float b3r = c3 * a3r - s3 * a3i, b3i = c3 * a3i + s3 * a3r;
    float t0r = a0r + b2r, t0i = a0i + b2i;
    float t1r = a0r - b2r, t1i = a0i - b2i;
    float t2r = b1r + b3r, t2i = b1i + b3i;
    float t3r = b1r - b3r, t3i = b1i - b3i;
    int j = ((i - k) << 2) + k;
    dr[SW(j)]         = t0r + t2r;        di[SW(j)]         = t0i + t2i;
    dr[SW(j + p)]     = t1r - sign * t3i; di[SW(j + p)]     = t1i + sign * t3r;
    dr[SW(j + 2 * p)] = t0r - t2r;        di[SW(j + 2 * p)] = t0i - t2i;
    dr[SW(j + 3 * p)] = t1r + sign * t3i; di[SW(j + 3 * p)] = t1i - sign * t3r;
    __syncthreads();
    float* tp;
    tp = sr; sr = dr; dr = tp;
    tp = si; si = di; di = tp;
    p <<= 2;
    inv_p *= 0.25f;
  }
}

// ---------------------------------------------------------------------------
// Generic 64x64-tile transpose: src (B x R x C) -> dst (B x C x R), fp32.
// ---------------------------------------------------------------------------
__global__ __launch_bounds__(256) void transpose_kernel(
    const float* __restrict__ src, float* __restrict__ dst, int R, int C) {
  __shared__ float tile[64][65];
  const int c0 = blockIdx.x * 64, r0 = blockIdx.y * 64, b = blockIdx.z;
  const int tid = threadIdx.x;
#pragma unroll
  for (int it = 0; it < 4; it++) {
    int g = it * 256 + tid;            // 1024 float4 granules
    int r = g >> 4, q = g & 15;
    float4 v = *(const float4*)(src + ((size_t)b * R + r0 + r) * C + c0 + q * 4);
    tile[q * 4 + 0][r] = v.x;
    tile[q * 4 + 1][r] = v.y;
    tile[q * 4 + 2][r] = v.z;
    tile[q * 4 + 3][r] = v.w;
  }
  __syncthreads();
#pragma unroll
  for (int it = 0; it < 4; it++) {
    int g = it * 256 + tid;
    int c = g >> 4, w = g & 15;
    float4 v = make_float4(tile[c][w * 4 + 0], tile[c][w * 4 + 1],
                           tile[c][w * 4 + 2], tile[c][w * 4 + 3]);
    *(float4*)(dst + ((size_t)b * C + c0 + c) * R + r0 + w * 4) = v;
  }
}

// ---------------------------------------------------------------------------
// Stage 0: build complex-as-real weights in MFMA fragment-contiguous layout.
// ---------------------------------------------------------------------------
__global__ __launch_bounds__(256) void prep_kernel(
    const float* __restrict__ w1, const float* __restrict__ w2,
    ushort_t* __restrict__ Bc) {
  int idx = blockIdx.x * 256 + threadIdx.x;        // [0, 2*4*147456)
  int layer = idx / 589824; int r = idx - layer * 589824;
  int kb = r / 147456;      int r2 = r - kb * 147456;
  int jc = r2 / 6144;       int r3 = r2 - jc * 6144;
  int kc = r3 / 512;        int r4 = r3 - kc * 512;
  int lane = r4 >> 3;       int e = r4 & 7;
  int j = jc * 16 + (lane & 15);
  int k = kc * 32 + (lane >> 4) * 8 + e;
  const float* w = layer ? w2 : w1;
  float v;
  if (k < 192) {
    v = (j < 192) ? w[(kb * 192 + k) * 192 + j]
                  : w[((4 + kb) * 192 + k) * 192 + (j - 192)];
  } else {
    int k2 = k - 192;
    v = (j < 192) ? -w[((4 + kb) * 192 + k2) * 192 + j]
                  :  w[(kb * 192 + k2) * 192 + (j - 192)];
  }
  Bc[idx] = f2bf(v);
}

// ---------------------------------------------------------------------------
// Stage 1: forward FFT, two real columns packed per workgroup (1024 thr).
// xT (b,c,n) fp32 -> Fr/Fi (b,c,n) bf16.
// ---------------------------------------------------------------------------
__global__ __launch_bounds__(1024, 8) void fft_fwd_kernel(
    const float* __restrict__ xT, ushort_t* __restrict__ Fr,
    ushort_t* __restrict__ Fi) {
  __shared__ float Ar[N_SEQ], Ai[N_SEQ], Br[N_SEQ], Bi[N_SEQ];
  const int q = blockIdx.x, b = blockIdx.y;        // q in [0,384)
  const int c1 = 2 * q;
  const int t = threadIdx.x;
  const float* p1 = xT + ((size_t)b * C_TOT + c1) * N_SEQ;
  const float* p2 = p1 + N_SEQ;
#pragma unroll
  for (int m = 0; m < 4; m++) {
    int i = t + m * 1024;
    Ar[SW(i)] = p1[i];
    Ai[SW(i)] = p2[i];
  }
  __syncthreads();
  stockham_soa4(Ar, Ai, Br, Bi, t, -1.0f);
  ushort_t* fr1 = Fr + ((size_t)b * C_TOT + c1) * N_SEQ;
  ushort_t* fi1 = Fi + ((size_t)b * C_TOT + c1) * N_SEQ;
#pragma unroll
  for (int m = 0; m < 4; m++) {
    int k = t + m * 1024;
    int km = (N_SEQ - k) & (N_SEQ - 1);
    float a = Ar[SW(k)], bb = Ai[SW(k)], c = Ar[SW(km)], d = Ai[SW(km)];
    fr1[k]         = f2bf(0.5f * (a + c));    // X1.re
    fi1[k]         = f2bf(0.5f * (bb - d));   // X1.im
    fr1[N_SEQ + k] = f2bf(0.5f * (bb + d));   // X2.re
    fi1[N_SEQ + k] = f2bf(0.5f * (c - a));    // X2.im
  }
}

// ---------------------------------------------------------------------------
// Stage 2 (FUSED): MFMA 2-layer complex MLP with in-kernel forward DFT-4
// across blocks + transpose staging. One wg = (b, kb, 64-n tile).
// 512 threads / 8 waves, __launch_bounds__(512,4): cap 128 VGPR, no spill
// (r9: VGPR 64, WRITE 98 MB). 2 wg x 8 waves = 16 waves/CU. Abuf rows
// addressed via AROW (8-row pad) to kill the 16-way staging-write conflict.
// ---------------------------------------------------------------------------
__global__ __launch_bounds__(512, 4) void mlp_kernel(
    const ushort_t* __restrict__ Fr, const ushort_t* __restrict__ Fi,
    const ushort_t* __restrict__ Bc,       // fragment-contiguous (see prep)
    const float* __restrict__ b1g, const float* __restrict__ b2g,
    ushort_t* __restrict__ Or, ushort_t* __restrict__ Oi) {
  __shared__ ushort_t Abuf[64 * APITCH + 64];
  const int nt = blockIdx.x, kb = blockIdx.y, b = blockIdx.z;
  const int n0 = nt * 64;
  const int tid = threadIdx.x;
  const int lane = tid & 63, wave = tid >> 6;       // wave in [0,8)
  const int fr = lane & 15, fg = lane >> 4;
  const int col0 = wave * 48;

  // ---- fused DFT-4 across channel blocks + 1/128 ortho scale + transpose ----
  {
    const size_t S = (size_t)BS * N_SEQ;
    const float s = 0.0078125f;                       // 1/128
#pragma unroll
    for (int it = 0; it < 3; it++) {
      int g = it * 512 + tid;            // 1536 granules = 192 d x 8 n-octets
      int d = g >> 3, n8 = g & 7;
      size_t bse = ((size_t)(b * C_TOT + d)) * N_SEQ + n0 + n8 * 8;
      bf16x8 y0r = *(const bf16x8*)(Fr + bse);
      bf16x8 y0i = *(const bf16x8*)(Fi + bse);
      bf16x8 y1r = *(const bf16x8*)(Fr + bse + S);
      bf16x8 y1i = *(const bf16x8*)(Fi + bse + S);
      bf16x8 y2r = *(const bf16x8*)(Fr + bse + 2 * S);
      bf16x8 y2i = *(const bf16x8*)(Fi + bse + 2 * S);
      bf16x8 y3r = *(const bf16x8*)(Fr + bse + 3 * S);
      bf16x8 y3i = *(const bf16x8*)(Fi + bse + 3 * S);
      int rb = AROW(n8 * 8) + d;        // rows n8*8..n8*8+7 share the pad term
#pragma unroll
      for (int e = 0; e < 8; e++) {
        float a0r = b2f((unsigned short)y0r[e]), a0i = b2f((unsigned short)y0i[e]);
        float a1r = b2f((unsigned short)y1r[e]), a1i = b2f((unsigned short)y1i[e]);
        float a2r = b2f((unsigned short)y2r[e]), a2i = b2f((unsigned short)y2i[e]);
        float a3r = b2f((unsigned short)y3r[e]), a3i = b2f((unsigned short)y3i[e]);
        float zr, zi;
        if (kb == 0)      { zr = a0r + a1r + a2r + a3r; zi = a0i + a1i + a2i + a3i; }
        else if (kb == 1) { zr = a0r + a1i - a2r - a3i; zi = a0i - a1r - a2i + a3r; }
        else if (kb == 2) { zr = a0r - a1r + a2r - a3r; zi = a0i - a1i + a2i - a3i; }
        else              { zr = a0r - a1i - a2r + a3i; zi = a0i + a1r - a2i - a3r; }
        Abuf[rb + e * APITCH]       = f2bf(zr * s);
        Abuf[rb + e * APITCH + 192] = f2bf(zi * s);
      }
    }
  }
  __syncthreads();

  // per-(layer,kb) fragment bases; wave owns cols [wave*48, wave*48+48)
  const ushort_t* B1 = Bc + (size_t)kb * 147456 + (size_t)wave * 18432 +
                       (size_t)lane * 8;
  const ushort_t* B2 = B1 + 589824;

  f32x4 acc[4][3];
  bf16x8 bf0[3], bf1[3], afr[4];

  auto loadB = [&](const ushort_t* Bb, int kc, bf16x8* dst) {
#pragma unroll
    for (int ct = 0; ct < 3; ct++)
      dst[ct] = *(const bf16x8*)(Bb + (size_t)kc * 512 + ct * 6144);
  };
  auto doK = [&](int kc, bf16x8* bw) {
#pragma unroll
    for (int rt = 0; rt < 4; rt++) {
      int ar = rt * 16 + fr;
      afr[rt] = *(const bf16x8*)(&Abuf[AROW(ar) + kc * 32 + fg * 8]);
    }
#pragma unroll
    for (int rt = 0; rt < 4; rt++)
#pragma unroll
      for (int ct = 0; ct < 3; ct++)
        acc[rt][ct] = __builtin_amdgcn_mfma_f32_16x16x32_bf16(
            afr[rt], bw[ct], acc[rt][ct], 0, 0, 0);
  };

  // ---- layer 1 ----
#pragma unroll
  for (int rt = 0; rt < 4; rt++)
#pragma unroll
    for (int ct = 0; ct < 3; ct++) acc[rt][ct] = 0.0f;
  loadB(B1, 0, bf0);
#pragma unroll
  for (int kc2 = 0; kc2 < 6; kc2++) {
    loadB(B1, 2 * kc2 + 1, bf1);
    doK(2 * kc2, bf0);
    if (kc2 < 5) loadB(B1, 2 * kc2 + 2, bf0);
    doK(2 * kc2 + 1, bf1);
  }

  // ---- H = relu(acc + b1) -> back into Abuf (bf16) ----
  __syncthreads();   // all waves done reading A
#pragma unroll
  for (int ct = 0; ct < 3; ct++) {
    int j = col0 + ct * 16 + fr;
    float bias = (j < 192) ? b1g[kb * 192 + j] : b1g[768 + kb * 192 + (j - 192)];
#pragma unroll
    for (int rt = 0; rt < 4; rt++)
#pragma unroll
      for (int reg = 0; reg < 4; reg++) {
        float v = acc[rt][ct][reg] + bias;
        v = fmaxf(v, 0.0f);
        int hrow = rt * 16 + fg * 4 + reg;
        Abuf[AROW(hrow) + j] = f2bf(v);
      }
  }
  __syncthreads();

  // ---- layer 2 ----
#pragma unroll
  for (int rt = 0; rt < 4; rt++)
#pragma unroll
    for (int ct = 0; ct < 3; ct++) acc[rt][ct] = 0.0f;
  loadB(B2, 0, bf0);
#pragma unroll
  for (int kc2 = 0; kc2 < 6; kc2++) {
    loadB(B2, 2 * kc2 + 1, bf1);
    doK(2 * kc2, bf0);
    if (kc2 < 5) loadB(B2, 2 * kc2 + 2, bf0);
    doK(2 * kc2 + 1, bf1);
  }

  // ---- epilogue: bias + softshrink -> bf16 planes (b,c,n) ----
#pragma unroll
  for (int ct = 0; ct < 3; ct++) {
    int j = col0 + ct * 16 + fr;
    float bias;
    ushort_t* plane;
    if (j < 192) {
      bias = b2g[kb * 192 + j];
      plane = Or + ((size_t)(b * C_TOT + kb * 192 + j)) * N_SEQ;
    } else {
      bias = b2g[768 + kb * 192 + (j - 192)];
      plane = Oi + ((size_t)(b * C_TOT + kb * 192 + (j - 192))) * N_SEQ;
    }
#pragma unroll
    for (int rt = 0; rt < 4; rt++) {
      short4v pk;
#pragma unroll
      for (int reg = 0; reg < 4; reg++) {
        float v = acc[rt][ct][reg] + bias;
        v = (v > LAMBDA) ? (v - LAMBDA) : ((v < -LAMBDA) ? (v + LAMBDA) : 0.0f);
        pk[reg] = (short)f2bf(v);
      }
      *(short4v*)(plane + n0 + rt * 16 + fg * 4) = pk;
    }
  }
}

// ---------------------------------------------------------------------------
// Stage 3 (FUSED): inverse FFT (1024 thr) with in-kernel inverse DFT-4 across
// blocks in the load phase. Output channel c1=2q maps to (spatial block
// jb = c1/192, d = c1%192); o_jb[d] = (1/128) * sum_kb z_kb[d] * i^(jb*kb).
// Then Hermitian projection + packed inverse FFT.
// ---------------------------------------------------------------------------
__global__ __launch_bounds__(1024, 8) void fft_inv_kernel(
    const ushort_t* __restrict__ Or, const ushort_t* __restrict__ Oi,
    float* __restrict__ yT) {
  __shared__ float Ar[N_SEQ], Ai[N_SEQ], Br[N_SEQ], Bi[N_SEQ];
  const int q = blockIdx.x, b = blockIdx.y;
  const int c1 = 2 * q;
  const int jb = c1 / 192;             // spatial block (same for c1, c1+1)
  const int d  = c1 - jb * 192;        // even
  const int t = threadIdx.x;
  const size_t S = (size_t)BS * N_SEQ;
  const float s = 1.0f / 128.0f;
  const size_t base0 = ((size_t)b * C_TOT + d) * N_SEQ;
  {
    int i0 = t * 4;                    // 1024 threads x 4 = 4096
#pragma unroll
    for (int col = 0; col < 2; col++) {
      size_t bse = base0 + (size_t)col * N_SEQ + i0;
      short4v z0r = *(const short4v*)(Or + bse);
      short4v z0i = *(const short4v*)(Oi + bse);
      short4v z1r = *(const short4v*)(Or + bse + S);
      short4v z1i = *(const short4v*)(Oi + bse + S);
      short4v z2r = *(const short4v*)(Or + bse + 2 * S);
      short4v z2i = *(const short4v*)(Oi + bse + 2 * S);
      short4v z3r = *(const short4v*)(Or + bse + 3 * S);
      short4v z3i = *(const short4v*)(Oi + bse + 3 * S);
      float* Dr = col ? Br : Ar;
      float* Di = col ? Bi : Ai;
#pragma unroll
      for (int e = 0; e < 4; e++) {
        float a0r = b2f((unsigned short)z0r[e]), a0i = b2f((unsigned short)z0i[e]);
        float a1r = b2f((unsigned short)z1r[e]), a1i = b2f((unsigned short)z1i[e]);
        float a2r = b2f((unsigned short)z2r[e]), a2i = b2f((unsigned short)z2i[e]);
        float a3r = b2f((unsigned short)z3r[e]), a3i = b2f((unsigned short)z3i[e]);
        float orr, oii;
        if (jb == 0)      { orr = a0r + a1r + a2r + a3r; oii = a0i + a1i + a2i + a3i; }
        else if (jb == 1) { orr = a0r - a1i - a2r + a3i; oii = a0i + a1r - a2i - a3r; }
        else if (jb == 2) { orr = a0r - a1r + a2r - a3r; oii = a0i - a1i + a2i - a3i; }
        else              { orr = a0r + a1i - a2r - a3i; oii = a0i - a1r - a2i + a3r; }
        int i = i0 + e;
        Dr[SW(i)] = orr * s;
        Di[SW(i)] = oii * s;
      }
    }
  }
  __syncthreads();
  float wr[4], wi[4];
#pragma unroll
  for (int m = 0; m < 4; m++) {
    int k = t + m * 1024;
    int km = (N_SEQ - k) & (N_SEQ - 1);
    float zh1r = 0.5f * (Ar[SW(k)] + Ar[SW(km)]);
    float zh1i = 0.5f * (Ai[SW(k)] - Ai[SW(km)]);
    float zh2r = 0.5f * (Br[SW(k)] + Br[SW(km)]);
    float zh2i = 0.5f * (Bi[SW(k)] - Bi[SW(km)]);
    wr[m] = zh1r - zh2i;
    wi[m] = zh1i + zh2r;
  }
  __syncthreads();
#pragma unroll
  for (int m = 0; m < 4; m++) {
    int k = t + m * 1024;
    Ar[SW(k)] = wr[m];
    Ai[SW(k)] = wi[m];
  }
  __syncthreads();
  stockham_soa4(Ar, Ai, Br, Bi, t, +1.0f);
  float* y1 = yT + ((size_t)b * C_TOT + c1) * N_SEQ;
#pragma unroll
  for (int m = 0; m < 4; m++) {
    int i = t + m * 1024;
    y1[i]         = Ar[SW(i)];
    y1[N_SEQ + i] = Ai[SW(i)];
  }
}

// ---------------------------------------------------------------------------
extern "C" void kernel_launch(void* const* d_in, const int* in_sizes, int n_in,
                              void* d_out, int out_size, void* d_ws, size_t ws_size,
                              hipStream_t stream) {
  const float* x  = (const float*)d_in[0];
  const float* w1 = (const float*)d_in[1];
  const float* b1 = (const float*)d_in[2];
  const float* w2 = (const float*)d_in[3];
  const float* b2 = (const float*)d_in[4];
  float* out = (float*)d_out;

  const size_t P = (size_t)B_BATCH * C_TOT * N_SEQ;       // 25,165,824 elems
  // ws layout (bytes):
  //   [0, 2P):   Fr (P bf16)            -> later yT low half
  //   [2P, 4P):  Fi (P bf16)            -> later yT high half
  //   [4P, 8P):  xT (P fp32)            -> later Or (P bf16) + Oi (P bf16)
  //   Bc at 8P: 2*589824 bf16
  // Serial reuse is safe: fft_fwd consumes xT before mlp writes Or/Oi there;
  // mlp consumes Fr/Fi before fft_inv writes yT there.
  const size_t need = 8 * P + 2 * 589824 * sizeof(ushort_t);  // 203,685,888 B
  if (ws_size < need) return;
  char* base = (char*)d_ws;
  ushort_t* Fr = (ushort_t*)base;
  ushort_t* Fi = (ushort_t*)(base + 2 * P);
  float*    xT = (float*)(base + 4 * P);
  ushort_t* Or = (ushort_t*)(base + 4 * P);
  ushort_t* Oi = (ushort_t*)(base + 6 * P);
  float*    yT = (float*)base;
  ushort_t* Bc = (ushort_t*)(base + 8 * P);

  hipLaunchKernelGGL(prep_kernel, dim3(4608), dim3(256), 0, stream, w1, w2, Bc);
  // x (b,n,c) -> xT (b,c,n)
  hipLaunchKernelGGL(transpose_kernel, dim3(C_TOT / 64, N_SEQ / 64, B_BATCH),
                     dim3(256), 0, stream, x, xT, N_SEQ, C_TOT);
  hipLaunchKernelGGL(fft_fwd_kernel, dim3(C_TOT / 2, B_BATCH), dim3(1024), 0,
                     stream, xT, Fr, Fi);
  hipLaunchKernelGGL(mlp_kernel, dim3(N_SEQ / 64, NBLK, B_BATCH), dim3(512),
                     0, stream, Fr, Fi, Bc, b1, b2, Or, Oi);
  hipLaunchKernelGGL(fft_inv_kernel, dim3(C_TOT / 2, B_BATCH), dim3(1024), 0,
                     stream, Or, Oi, yT);
  // yT (b,c,n) -> out (b,n,c)
  hipLaunchKernelGGL(transpose_kernel, dim3(N_SEQ / 64, C_TOT / 64, B_BATCH),
                     dim3(256), 0, stream, yT, out, C_TOT, N_SEQ);
}